// Round 2
// baseline (249.216 us; speedup 1.0000x reference)
//
#include <hip/hip_runtime.h>

#define S_DIM 128
#define N_DIM 256
#define CIN   256
#define CH    32
#define COUT  128

typedef __attribute__((ext_vector_type(8))) short bf16x8;
typedef __attribute__((ext_vector_type(4))) float f32x4;

__device__ __forceinline__ unsigned short f2bf(float f) {
  union { float f; unsigned int u; } v; v.f = f;
  unsigned int u = v.u;
  return (unsigned short)((u + 0x7FFFu + ((u >> 16) & 1u)) >> 16);
}

// ---------------------------------------------------------------------------
// Kernel 1: prep — rnm (1/clip(mask^T mask,1)), bf16 conversions of Wa/Wb/Wo
// blocks 0..63: wab rows; 64..191: Wo rows; 192..447: rnm rows
// ---------------------------------------------------------------------------
__global__ __launch_bounds__(256) void prep_kernel(
    const float* __restrict__ mask, const float* __restrict__ Wa,
    const float* __restrict__ Wb, const float* __restrict__ Wo,
    float* __restrict__ rnm, unsigned short* __restrict__ wab,
    unsigned short* __restrict__ wo_bf) {
  const int b = blockIdx.x, t = threadIdx.x;
  if (b < 64) {
    const float* src = (b < 32) ? (Wa + b * CIN) : (Wb + (b - 32) * CIN);
    wab[b * CIN + t] = f2bf(src[t]);
  } else if (b < 192) {
    const int r = b - 64;  // 0..127
    #pragma unroll
    for (int q = 0; q < 4; q++) {
      const int k = q * 256 + t;
      wo_bf[r * 1024 + k] = f2bf(Wo[r * 1024 + k]);
    }
  } else {
    const int i = b - 192;  // 0..255
    float acc = 0.f;
    for (int s = 0; s < S_DIM; s++)
      acc += mask[s * N_DIM + i] * mask[s * N_DIM + t];
    acc = fmaxf(acc, 1.0f);
    rnm[i * N_DIM + t] = 1.0f / acc;
  }
}

// ---------------------------------------------------------------------------
// Kernel 2: LayerNorm + projection to a,b (bf16, transposed layout)
// a_t[(i*32+c)][s], b_t[(i*32+c)][s]   (8192 x 128 bf16 each)
// grid (256 i, 4 s-quarters), 256 threads = 4 waves
// ---------------------------------------------------------------------------
__global__ __launch_bounds__(256) void lnproj_kernel(
    const float* __restrict__ m, const float* __restrict__ mask,
    const float* __restrict__ gamma, const float* __restrict__ beta,
    const unsigned short* __restrict__ wab,
    unsigned short* __restrict__ a_t, unsigned short* __restrict__ b_t) {
  constexpr int PADK = CIN + 8;  // stride 264 elems = 132 words -> 2-way (free)
  __shared__ __align__(16) unsigned short mn[32][PADK];
  const int i = blockIdx.x;
  const int s0 = blockIdx.y * 32;
  const int t = threadIdx.x, w = t >> 6, l = t & 63;
  const int lq = l >> 4, lr = l & 15;

  const float4 g4 = *(const float4*)(gamma + l * 4);
  const float4 b4 = *(const float4*)(beta + l * 4);

  // Phase 1: wave-per-row LN, mask folded in (projection is linear)
  for (int rr = 0; rr < 8; rr++) {
    const int r = w * 8 + rr;
    const int s = s0 + r;
    const float4 v = *(const float4*)(m + ((size_t)(s * N_DIM + i)) * CIN + l * 4);
    float sum = v.x + v.y + v.z + v.w;
    float sq  = v.x * v.x + v.y * v.y + v.z * v.z + v.w * v.w;
    #pragma unroll
    for (int off = 32; off > 0; off >>= 1) {
      sum += __shfl_down(sum, off);
      sq  += __shfl_down(sq, off);
    }
    sum = __shfl(sum, 0); sq = __shfl(sq, 0);
    const float mu = sum * (1.0f / CIN);
    const float var = fmaxf(sq * (1.0f / CIN) - mu * mu, 0.0f);
    const float rs = rsqrtf(var + 1e-5f);
    const float mk = mask[s * N_DIM + i];
    ushort4 p;
    p.x = f2bf(((v.x - mu) * rs * g4.x + b4.x) * mk);
    p.y = f2bf(((v.y - mu) * rs * g4.y + b4.y) * mk);
    p.z = f2bf(((v.z - mu) * rs * g4.z + b4.z) * mk);
    p.w = f2bf(((v.w - mu) * rs * g4.w + b4.w) * mk);
    *(ushort4*)(&mn[r][l * 4]) = p;
  }
  __syncthreads();

  // Phase 2: MFMA  (M=32 rows, N=64 outputs [Wa|Wb], K=256)
  const int wm = w & 1;   // m-tile
  const int n2 = w >> 1;  // 0 -> a, 1 -> b
  f32x4 acc0 = {0.f, 0.f, 0.f, 0.f}, acc1 = {0.f, 0.f, 0.f, 0.f};
  #pragma unroll
  for (int ks = 0; ks < 8; ks++) {        // K = 256 = 8 * 32
    const int k0 = ks * 32 + lq * 8;
    const bf16x8 af = *(const bf16x8*)(&mn[wm * 16 + lr][k0]);
    const unsigned short* wrow = wab + (n2 * 32 + lr) * CIN + k0;
    const bf16x8 bf0 = *(const bf16x8*)(wrow);
    const bf16x8 bf1 = *(const bf16x8*)(wrow + 16 * CIN);
    acc0 = __builtin_amdgcn_mfma_f32_16x16x32_bf16(af, bf0, acc0, 0, 0, 0);
    acc1 = __builtin_amdgcn_mfma_f32_16x16x32_bf16(af, bf1, acc1, 0, 0, 0);
  }

  // C/D: col(=c) = lane&15, row(=s_local) = quad*4 + reg  -> 4 consecutive s
  unsigned short* dst = (n2 == 0) ? a_t : b_t;
  const int scol = s0 + wm * 16 + lq * 4;
  ushort4 q0, q1;
  q0.x = f2bf(acc0[0]); q0.y = f2bf(acc0[1]); q0.z = f2bf(acc0[2]); q0.w = f2bf(acc0[3]);
  q1.x = f2bf(acc1[0]); q1.y = f2bf(acc1[1]); q1.z = f2bf(acc1[2]); q1.w = f2bf(acc1[3]);
  *(ushort4*)(dst + ((size_t)(i * CH + lr)) * S_DIM + scol) = q0;
  *(ushort4*)(dst + ((size_t)(i * CH + 16 + lr)) * S_DIM + scol) = q1;
}

// ---------------------------------------------------------------------------
// Kernel 3: fused z-GEMM + Wo contraction
// block = 128x128 z-tile (4 i x 4 j = 16 pairs), 256 threads = 4 waves
// LDS: sA/sB 64KB (XOR-swizzled granules), reused as sZ (16 x 1024 bf16)
// ---------------------------------------------------------------------------
__global__ __launch_bounds__(256) void fused_kernel(
    const unsigned short* __restrict__ a_t, const unsigned short* __restrict__ b_t,
    const unsigned short* __restrict__ wo_bf, const float* __restrict__ rnm,
    const float* __restrict__ bo, float* __restrict__ out) {
  __shared__ __align__(16) unsigned short sA[128 * 128];
  __shared__ __align__(16) unsigned short sB[128 * 128];
  const int t = threadIdx.x, w = t >> 6, l = t & 63;
  const int lq = l >> 4, lr = l & 15;
  const int bx = blockIdx.x, by = blockIdx.y;

  // Stage A/B tiles (contiguous 32KB each), swizzle 16B granules: g' = g ^ (r&15)
  const unsigned short* srcA = a_t + (size_t)bx * (128 * 128);
  const unsigned short* srcB = b_t + (size_t)by * (128 * 128);
  #pragma unroll
  for (int it = 0; it < 8; it++) {
    const int idx = it * 256 + t;          // granule 0..2047
    const int r = idx >> 4, g = idx & 15;
    const int dst = r * 128 + ((g ^ (r & 15)) * 8);
    *(bf16x8*)(&sA[dst]) = *(const bf16x8*)(srcA + idx * 8);
    *(bf16x8*)(&sB[dst]) = *(const bf16x8*)(srcB + idx * 8);
  }
  __syncthreads();

  // GEMM1: z[(i,c)][(j,d)] = sum_s a_t * b_t ; wave quadrant 64x64
  const int wmb = (w & 1) * 64, wnb = (w >> 1) * 64;
  f32x4 acc[4][4];
  #pragma unroll
  for (int a = 0; a < 4; a++)
    #pragma unroll
    for (int b = 0; b < 4; b++) acc[a][b] = (f32x4){0.f, 0.f, 0.f, 0.f};

  // K = S_DIM = 128 = 4 MFMA steps of 32 (16 granules/row). NOT 8 — rows are
  // only 128 elements; ks=4..7 would read the next row (round-1 bug).
  #pragma unroll
  for (int ks = 0; ks < 4; ks++) {
    const int g0 = ks * 4 + lq;
    bf16x8 afr[4], bfr[4];
    #pragma unroll
    for (int a = 0; a < 4; a++) {
      const int ra = wmb + a * 16 + lr;
      afr[a] = *(const bf16x8*)(&sA[ra * 128 + ((g0 ^ (ra & 15)) * 8)]);
      const int rb = wnb + a * 16 + lr;
      bfr[a] = *(const bf16x8*)(&sB[rb * 128 + ((g0 ^ (rb & 15)) * 8)]);
    }
    #pragma unroll
    for (int a = 0; a < 4; a++)
      #pragma unroll
      for (int b = 0; b < 4; b++)
        acc[a][b] = __builtin_amdgcn_mfma_f32_16x16x32_bf16(afr[a], bfr[b], acc[a][b], 0, 0, 0);
  }
  __syncthreads();

  // z (C/D layout) -> sZ[pair][cd] bf16, swizzled low-4 of granule with pair
  unsigned short* sZ = sA;  // 16*1024 = 16384 entries = exactly sA
  #pragma unroll
  for (int a = 0; a < 4; a++) {
    #pragma unroll
    for (int b = 0; b < 4; b++) {
      #pragma unroll
      for (int r = 0; r < 4; r++) {
        const int zr = wmb + a * 16 + lq * 4 + r;   // (i_loc, c)
        const int zc = wnb + b * 16 + lr;           // (j_loc, d)
        const int pair = (zr >> 5) * 4 + (zc >> 5);
        const int k = (zr & 31) * 32 + (zc & 31);
        const int g = k >> 3;
        const int sw = (g & ~15) | ((g & 15) ^ pair);
        sZ[pair * 1024 + sw * 8 + (k & 7)] = f2bf(acc[a][b][r]);
      }
    }
  }
  __syncthreads();

  // GEMM2: out[pair][o] = sum_k z[pair][k] * Wo[o][k]  (M=16,N=128,K=1024)
  f32x4 oa0 = {0.f, 0.f, 0.f, 0.f}, oa1 = {0.f, 0.f, 0.f, 0.f};
  const unsigned short* wrow0 = wo_bf + (size_t)(w * 32 + lr) * 1024 + lq * 8;
  const unsigned short* wrow1 = wrow0 + 16 * 1024;
  #pragma unroll 4
  for (int kk = 0; kk < 32; kk++) {
    const int g0 = kk * 4 + lq;
    const int sw = (g0 & ~15) | ((g0 & 15) ^ lr);
    const bf16x8 zf = *(const bf16x8*)(&sZ[lr * 1024 + sw * 8]);
    const bf16x8 w0 = *(const bf16x8*)(wrow0 + kk * 32);
    const bf16x8 w1 = *(const bf16x8*)(wrow1 + kk * 32);
    oa0 = __builtin_amdgcn_mfma_f32_16x16x32_bf16(zf, w0, oa0, 0, 0, 0);
    oa1 = __builtin_amdgcn_mfma_f32_16x16x32_bf16(zf, w1, oa1, 0, 0, 0);
  }

  // Epilogue: scale by 1/nm, add bias, store fp32
  const int o0 = w * 32 + lr;
  const float bo0 = bo[o0], bo1 = bo[o0 + 16];
  #pragma unroll
  for (int r = 0; r < 4; r++) {
    const int pair = lq * 4 + r;
    const int ii = bx * 4 + (pair >> 2);
    const int jj = by * 4 + (pair & 3);
    const float sc = rnm[ii * N_DIM + jj];
    float* orow = out + ((size_t)(ii * N_DIM + jj)) * COUT;
    orow[o0]      = oa0[r] * sc + bo0;
    orow[o0 + 16] = oa1[r] * sc + bo1;
  }
}

// ---------------------------------------------------------------------------
extern "C" void kernel_launch(void* const* d_in, const int* in_sizes, int n_in,
                              void* d_out, int out_size, void* d_ws, size_t ws_size,
                              hipStream_t stream) {
  const float* m     = (const float*)d_in[0];
  const float* mask  = (const float*)d_in[1];
  const float* gamma = (const float*)d_in[2];
  const float* beta  = (const float*)d_in[3];
  const float* Wa    = (const float*)d_in[4];
  const float* Wb    = (const float*)d_in[5];
  const float* Wo    = (const float*)d_in[6];
  const float* bo    = (const float*)d_in[7];
  float* out = (float*)d_out;

  char* ws = (char*)d_ws;
  float*          rnm   = (float*)(ws);                    // 256 KB
  unsigned short* wab   = (unsigned short*)(ws + 262144);  //  32 KB
  unsigned short* wo_bf = (unsigned short*)(ws + 294912);  // 256 KB
  unsigned short* a_t   = (unsigned short*)(ws + 557056);  //   2 MB
  unsigned short* b_t   = (unsigned short*)(ws + 2654208); //   2 MB
  // total ws use: ~4.65 MB

  prep_kernel<<<448, 256, 0, stream>>>(mask, Wa, Wb, Wo, rnm, wab, wo_bf);
  lnproj_kernel<<<dim3(256, 4), 256, 0, stream>>>(m, mask, gamma, beta, wab, a_t, b_t);
  fused_kernel<<<dim3(64, 64), 256, 0, stream>>>(a_t, b_t, wo_bf, rnm, bo, out);
}

// Round 3
// 233.957 us; speedup vs baseline: 1.0652x; 1.0652x over previous
//
#include <hip/hip_runtime.h>

#define S_DIM 128
#define N_DIM 256
#define CIN   256
#define CH    32
#define COUT  128

typedef __attribute__((ext_vector_type(8))) short bf16x8;
typedef __attribute__((ext_vector_type(4))) float f32x4;

__device__ __forceinline__ unsigned short f2bf(float f) {
  union { float f; unsigned int u; } v; v.f = f;
  unsigned int u = v.u;
  return (unsigned short)((u + 0x7FFFu + ((u >> 16) & 1u)) >> 16);
}

// ---------------------------------------------------------------------------
// Kernel 1: prep — rnm (1/clip(mask^T mask,1)), bf16 conversions.
// wo_bf is stored K-TRANSPOSED: wo_bf[o][d*32+c] = Wo[o][c*32+d], matching the
// z^T LDS layout the fused kernel's transpose phase produces.
// ---------------------------------------------------------------------------
__global__ __launch_bounds__(256) void prep_kernel(
    const float* __restrict__ mask, const float* __restrict__ Wa,
    const float* __restrict__ Wb, const float* __restrict__ Wo,
    float* __restrict__ rnm, unsigned short* __restrict__ wab,
    unsigned short* __restrict__ wo_bf) {
  const int b = blockIdx.x, t = threadIdx.x;
  if (b < 64) {
    const float* src = (b < 32) ? (Wa + b * CIN) : (Wb + (b - 32) * CIN);
    wab[b * CIN + t] = f2bf(src[t]);
  } else if (b < 192) {
    const int r = b - 64;  // 0..127
    #pragma unroll
    for (int q = 0; q < 4; q++) {
      const int k = q * 256 + t;          // k' = d*32 + c
      const int c = k & 31, d = k >> 5;
      wo_bf[r * 1024 + k] = f2bf(Wo[r * 1024 + c * 32 + d]);
    }
  } else {
    const int i = b - 192;  // 0..255
    float acc = 0.f;
    #pragma unroll 8
    for (int s = 0; s < S_DIM; s++)
      acc += mask[s * N_DIM + i] * mask[s * N_DIM + t];
    acc = fmaxf(acc, 1.0f);
    rnm[i * N_DIM + t] = 1.0f / acc;
  }
}

// ---------------------------------------------------------------------------
// Kernel 2: LayerNorm + projection to a,b (bf16, transposed layout)
// a_t[(i*32+c)][s], b_t[(i*32+c)][s]   (8192 x 128 bf16 each)
// ---------------------------------------------------------------------------
__global__ __launch_bounds__(256) void lnproj_kernel(
    const float* __restrict__ m, const float* __restrict__ mask,
    const float* __restrict__ gamma, const float* __restrict__ beta,
    const unsigned short* __restrict__ wab,
    unsigned short* __restrict__ a_t, unsigned short* __restrict__ b_t) {
  constexpr int PADK = CIN + 8;
  __shared__ __align__(16) unsigned short mn[32][PADK];
  const int i = blockIdx.x;
  const int s0 = blockIdx.y * 32;
  const int t = threadIdx.x, w = t >> 6, l = t & 63;
  const int lq = l >> 4, lr = l & 15;

  const float4 g4 = *(const float4*)(gamma + l * 4);
  const float4 b4 = *(const float4*)(beta + l * 4);

  for (int rr = 0; rr < 8; rr++) {
    const int r = w * 8 + rr;
    const int s = s0 + r;
    const float4 v = *(const float4*)(m + ((size_t)(s * N_DIM + i)) * CIN + l * 4);
    float sum = v.x + v.y + v.z + v.w;
    float sq  = v.x * v.x + v.y * v.y + v.z * v.z + v.w * v.w;
    #pragma unroll
    for (int off = 32; off > 0; off >>= 1) {
      sum += __shfl_down(sum, off);
      sq  += __shfl_down(sq, off);
    }
    sum = __shfl(sum, 0); sq = __shfl(sq, 0);
    const float mu = sum * (1.0f / CIN);
    const float var = fmaxf(sq * (1.0f / CIN) - mu * mu, 0.0f);
    const float rs = rsqrtf(var + 1e-5f);
    const float mk = mask[s * N_DIM + i];
    ushort4 p;
    p.x = f2bf(((v.x - mu) * rs * g4.x + b4.x) * mk);
    p.y = f2bf(((v.y - mu) * rs * g4.y + b4.y) * mk);
    p.z = f2bf(((v.z - mu) * rs * g4.z + b4.z) * mk);
    p.w = f2bf(((v.w - mu) * rs * g4.w + b4.w) * mk);
    *(ushort4*)(&mn[r][l * 4]) = p;
  }
  __syncthreads();

  const int wm = w & 1;
  const int n2 = w >> 1;
  f32x4 acc0 = {0.f, 0.f, 0.f, 0.f}, acc1 = {0.f, 0.f, 0.f, 0.f};
  #pragma unroll
  for (int ks = 0; ks < 8; ks++) {
    const int k0 = ks * 32 + lq * 8;
    const bf16x8 af = *(const bf16x8*)(&mn[wm * 16 + lr][k0]);
    const unsigned short* wrow = wab + (n2 * 32 + lr) * CIN + k0;
    const bf16x8 bf0 = *(const bf16x8*)(wrow);
    const bf16x8 bf1 = *(const bf16x8*)(wrow + 16 * CIN);
    acc0 = __builtin_amdgcn_mfma_f32_16x16x32_bf16(af, bf0, acc0, 0, 0, 0);
    acc1 = __builtin_amdgcn_mfma_f32_16x16x32_bf16(af, bf1, acc1, 0, 0, 0);
  }

  unsigned short* dst = (n2 == 0) ? a_t : b_t;
  const int scol = s0 + wm * 16 + lq * 4;
  ushort4 q0, q1;
  q0.x = f2bf(acc0[0]); q0.y = f2bf(acc0[1]); q0.z = f2bf(acc0[2]); q0.w = f2bf(acc0[3]);
  q1.x = f2bf(acc1[0]); q1.y = f2bf(acc1[1]); q1.z = f2bf(acc1[2]); q1.w = f2bf(acc1[3]);
  *(ushort4*)(dst + ((size_t)(i * CH + lr)) * S_DIM + scol) = q0;
  *(ushort4*)(dst + ((size_t)(i * CH + 16 + lr)) * S_DIM + scol) = q1;
}

// ---------------------------------------------------------------------------
// Kernel 3: fused z-GEMM + Wo contraction.  512 threads = 8 waves,
// 64 KB LDS -> 2 blocks/CU = 16 waves/CU (~50% occupancy, was 22%).
// GEMM1: wave grid 2x4, each wave a 64x32 quadrant of the 128x128 z-tile.
// Transpose: b64 writes into sZ[pair][k'=d*32+c] with XOR-swizzled granules.
// GEMM2: wave w handles o-tile w*16..w*16+15, 4 accumulator chains.
// ---------------------------------------------------------------------------
__global__ __launch_bounds__(512, 4) void fused_kernel(
    const unsigned short* __restrict__ a_t, const unsigned short* __restrict__ b_t,
    const unsigned short* __restrict__ wo_bf, const float* __restrict__ rnm,
    const float* __restrict__ bo, float* __restrict__ out) {
  __shared__ __align__(16) unsigned short sA[128 * 128];
  __shared__ __align__(16) unsigned short sB[128 * 128];
  const int t = threadIdx.x, w = t >> 6, l = t & 63;
  const int lq = l >> 4, lr = l & 15;
  const int bx = blockIdx.x, by = blockIdx.y;

  // Stage A/B tiles (32 KB each); swizzle 16B granules: g' = g ^ (r&15)
  const unsigned short* srcA = a_t + (size_t)bx * (128 * 128);
  const unsigned short* srcB = b_t + (size_t)by * (128 * 128);
  #pragma unroll
  for (int it = 0; it < 4; it++) {
    const int idx = it * 512 + t;          // granule 0..2047
    const int r = idx >> 4, g = idx & 15;
    const int dst = r * 128 + ((g ^ (r & 15)) * 8);
    *(bf16x8*)(&sA[dst]) = *(const bf16x8*)(srcA + idx * 8);
    *(bf16x8*)(&sB[dst]) = *(const bf16x8*)(srcB + idx * 8);
  }
  __syncthreads();

  // GEMM1: K = 128 = 4 MFMA steps of 32. Wave quadrant 64(m) x 32(n).
  const int wmb = (w & 1) * 64, wnb = (w >> 1) * 32;
  f32x4 acc[4][2];
  #pragma unroll
  for (int a = 0; a < 4; a++)
    #pragma unroll
    for (int b = 0; b < 2; b++) acc[a][b] = (f32x4){0.f, 0.f, 0.f, 0.f};

  #pragma unroll
  for (int ks = 0; ks < 4; ks++) {
    const int g0 = ks * 4 + lq;
    bf16x8 afr[4], bfr[2];
    #pragma unroll
    for (int a = 0; a < 4; a++) {
      const int ra = wmb + a * 16 + lr;
      afr[a] = *(const bf16x8*)(&sA[ra * 128 + ((g0 ^ (ra & 15)) * 8)]);
    }
    #pragma unroll
    for (int b = 0; b < 2; b++) {
      const int rb = wnb + b * 16 + lr;
      bfr[b] = *(const bf16x8*)(&sB[rb * 128 + ((g0 ^ (rb & 15)) * 8)]);
    }
    #pragma unroll
    for (int a = 0; a < 4; a++)
      #pragma unroll
      for (int b = 0; b < 2; b++)
        acc[a][b] = __builtin_amdgcn_mfma_f32_16x16x32_bf16(afr[a], bfr[b], acc[a][b], 0, 0, 0);
  }
  __syncthreads();

  // Transpose z (C/D layout) -> sZ[pair][k'=d*32+c], b64 (ushort4) writes.
  // Granule (16B) map: MAP(g,row) = (g&~7) | ((g ^ (g>>3) ^ row) & 7)
  unsigned short* sZ = sA;  // 16 pairs * 1024 shorts = 32 KB = sA exactly
  #pragma unroll
  for (int a = 0; a < 4; a++) {
    #pragma unroll
    for (int b = 0; b < 2; b++) {
      const int zrb = wmb + a * 16 + lq * 4;   // c-coordinate base (r = 0..3)
      const int zc  = wnb + b * 16 + lr;       // d-coordinate
      const int pair = (zrb >> 5) * 4 + (zc >> 5);
      const int off = (zc & 31) * 32 + (zrb & 31);  // shorts; multiple of 4
      const int g = off >> 3;
      const int gp = (g & ~7) | ((g ^ (g >> 3) ^ pair) & 7);
      ushort4 q;
      q.x = f2bf(acc[a][b][0]); q.y = f2bf(acc[a][b][1]);
      q.z = f2bf(acc[a][b][2]); q.w = f2bf(acc[a][b][3]);
      *(ushort4*)(&sZ[pair * 1024 + gp * 8 + (off & 7)]) = q;
    }
  }
  __syncthreads();

  // GEMM2: out[pair][o] = sum_k z^T-layout dot wo_bf (already k-transposed).
  // M=16 pairs (A rows = lr), N=16 o per wave (B rows = lr), K=1024.
  f32x4 oac[4];
  #pragma unroll
  for (int c = 0; c < 4; c++) oac[c] = (f32x4){0.f, 0.f, 0.f, 0.f};
  const unsigned short* wrow = wo_bf + (size_t)(w * 16 + lr) * 1024;
  #pragma unroll
  for (int kk = 0; kk < 32; kk++) {
    const int g = kk * 4 + lq;
    const int gp = (g & ~7) | ((g ^ (g >> 3) ^ lr) & 7);
    const bf16x8 zf = *(const bf16x8*)(&sZ[lr * 1024 + gp * 8]);
    const bf16x8 wf = *(const bf16x8*)(wrow + kk * 32 + lq * 8);
    oac[kk & 3] = __builtin_amdgcn_mfma_f32_16x16x32_bf16(zf, wf, oac[kk & 3], 0, 0, 0);
  }

  // Epilogue: D row = pair (lq*4+r), col = o (w*16+lr)
  const int o = w * 16 + lr;
  const float bov = bo[o];
  #pragma unroll
  for (int r = 0; r < 4; r++) {
    const int pair = lq * 4 + r;
    const int ii = bx * 4 + (pair >> 2);
    const int jj = by * 4 + (pair & 3);
    const float sc = rnm[ii * N_DIM + jj];
    out[((size_t)(ii * N_DIM + jj)) * COUT + o] =
        (oac[0][r] + oac[1][r] + oac[2][r] + oac[3][r]) * sc + bov;
  }
}

// ---------------------------------------------------------------------------
extern "C" void kernel_launch(void* const* d_in, const int* in_sizes, int n_in,
                              void* d_out, int out_size, void* d_ws, size_t ws_size,
                              hipStream_t stream) {
  const float* m     = (const float*)d_in[0];
  const float* mask  = (const float*)d_in[1];
  const float* gamma = (const float*)d_in[2];
  const float* beta  = (const float*)d_in[3];
  const float* Wa    = (const float*)d_in[4];
  const float* Wb    = (const float*)d_in[5];
  const float* Wo    = (const float*)d_in[6];
  const float* bo    = (const float*)d_in[7];
  float* out = (float*)d_out;

  char* ws = (char*)d_ws;
  float*          rnm   = (float*)(ws);                    // 256 KB
  unsigned short* wab   = (unsigned short*)(ws + 262144);  //  32 KB
  unsigned short* wo_bf = (unsigned short*)(ws + 294912);  // 256 KB
  unsigned short* a_t   = (unsigned short*)(ws + 557056);  //   2 MB
  unsigned short* b_t   = (unsigned short*)(ws + 2654208); //   2 MB

  prep_kernel<<<448, 256, 0, stream>>>(mask, Wa, Wb, Wo, rnm, wab, wo_bf);
  lnproj_kernel<<<dim3(256, 4), 256, 0, stream>>>(m, mask, gamma, beta, wab, a_t, b_t);
  fused_kernel<<<dim3(64, 64), 512, 0, stream>>>(a_t, b_t, wo_bf, rnm, bo, out);
}

// Round 4
// 147.662 us; speedup vs baseline: 1.6877x; 1.5844x over previous
//
#include <hip/hip_runtime.h>

#define S_DIM 128
#define N_DIM 256
#define CIN   256
#define CH    32
#define COUT  128

typedef __attribute__((ext_vector_type(8))) short bf16x8;
typedef __attribute__((ext_vector_type(4))) float f32x4;

__device__ __forceinline__ unsigned short f2bf(float f) {
  union { float f; unsigned int u; } v; v.f = f;
  unsigned int u = v.u;
  return (unsigned short)((u + 0x7FFFu + ((u >> 16) & 1u)) >> 16);
}

// ---------------------------------------------------------------------------
// Kernel A: merged LN+projection and prep.
//   blocks 0..1023   : LayerNorm + MFMA projection (wab converted block-locally
//                      into LDS -> no prep->lnproj kernel dependency)
//   blocks 1024..1151: wo2 = Wo bf16, permuted to [ot][kk][lane][8] so GEMM2's
//                      B-fragment load is one fully-coalesced 16B/lane read.
//                      k is also c/d-transposed (k' = d*32+c) to match sZ.
//   blocks 1152..1407: rnm = 1 / clip(mask^T mask, 1)
// ---------------------------------------------------------------------------
__global__ __launch_bounds__(256) void lnp_prep_kernel(
    const float* __restrict__ m, const float* __restrict__ mask,
    const float* __restrict__ gamma, const float* __restrict__ beta,
    const float* __restrict__ Wa, const float* __restrict__ Wb,
    const float* __restrict__ Wo,
    float* __restrict__ rnm, unsigned short* __restrict__ wo2,
    unsigned short* __restrict__ a_t, unsigned short* __restrict__ b_t) {
  const int b = blockIdx.x, t = threadIdx.x;
  if (b < 1024) {
    __shared__ __align__(16) unsigned short mn[32][264];   // +8 pad: 2-way free
    __shared__ __align__(16) unsigned short wabs[64 * 256];
    const int i = b & 255, s0 = (b >> 8) * 32;
    const int w = t >> 6, l = t & 63, lq = l >> 4, lr = l & 15;

    // Convert Wa/Wb -> wabs, granule-swizzled: g' = (g&16)|((g ^ (r&15))&15)
    #pragma unroll
    for (int it = 0; it < 8; it++) {
      const int gi = it * 256 + t;       // granule 0..2047 (64 rows x 32)
      const int r = gi >> 5, g = gi & 31;
      const float* src = (r < 32) ? (Wa + r * 256 + g * 8)
                                  : (Wb + (r - 32) * 256 + g * 8);
      const int gp = (g & 16) | ((g ^ (r & 15)) & 15);
      unsigned short* dst = &wabs[r * 256 + gp * 8];
      const float4 v0 = *(const float4*)(src);
      const float4 v1 = *(const float4*)(src + 4);
      dst[0] = f2bf(v0.x); dst[1] = f2bf(v0.y); dst[2] = f2bf(v0.z); dst[3] = f2bf(v0.w);
      dst[4] = f2bf(v1.x); dst[5] = f2bf(v1.y); dst[6] = f2bf(v1.z); dst[7] = f2bf(v1.w);
    }

    const float4 g4 = *(const float4*)(gamma + l * 4);
    const float4 b4 = *(const float4*)(beta + l * 4);

    // Wave-per-row LN, mask folded in (projection is linear)
    for (int rr = 0; rr < 8; rr++) {
      const int r = w * 8 + rr;
      const int s = s0 + r;
      const float4 v = *(const float4*)(m + ((size_t)(s * N_DIM + i)) * CIN + l * 4);
      float sum = v.x + v.y + v.z + v.w;
      float sq  = v.x * v.x + v.y * v.y + v.z * v.z + v.w * v.w;
      #pragma unroll
      for (int off = 32; off > 0; off >>= 1) {
        sum += __shfl_down(sum, off);
        sq  += __shfl_down(sq, off);
      }
      sum = __shfl(sum, 0); sq = __shfl(sq, 0);
      const float mu = sum * (1.0f / CIN);
      const float var = fmaxf(sq * (1.0f / CIN) - mu * mu, 0.0f);
      const float rs = rsqrtf(var + 1e-5f);
      const float mk = mask[s * N_DIM + i];
      ushort4 p;
      p.x = f2bf(((v.x - mu) * rs * g4.x + b4.x) * mk);
      p.y = f2bf(((v.y - mu) * rs * g4.y + b4.y) * mk);
      p.z = f2bf(((v.z - mu) * rs * g4.z + b4.z) * mk);
      p.w = f2bf(((v.w - mu) * rs * g4.w + b4.w) * mk);
      *(ushort4*)(&mn[r][l * 4]) = p;
    }
    __syncthreads();

    // MFMA: M=32 s-rows, N=64 [Wa|Wb], K=256
    const int wm = w & 1;
    const int n2 = w >> 1;
    f32x4 acc0 = {0.f, 0.f, 0.f, 0.f}, acc1 = {0.f, 0.f, 0.f, 0.f};
    #pragma unroll
    for (int ks = 0; ks < 8; ks++) {
      const int k0 = ks * 32 + lq * 8;
      const int g = ks * 4 + lq;                       // granule 0..31
      const int gp = (g & 16) | ((g ^ lr) & 15);       // row&15 == lr
      const bf16x8 af = *(const bf16x8*)(&mn[wm * 16 + lr][k0]);
      const bf16x8 bf0 = *(const bf16x8*)(&wabs[(n2 * 32 + lr) * 256 + gp * 8]);
      const bf16x8 bf1 = *(const bf16x8*)(&wabs[(n2 * 32 + 16 + lr) * 256 + gp * 8]);
      acc0 = __builtin_amdgcn_mfma_f32_16x16x32_bf16(af, bf0, acc0, 0, 0, 0);
      acc1 = __builtin_amdgcn_mfma_f32_16x16x32_bf16(af, bf1, acc1, 0, 0, 0);
    }

    unsigned short* dst = (n2 == 0) ? a_t : b_t;
    const int scol = s0 + wm * 16 + lq * 4;
    ushort4 q0, q1;
    q0.x = f2bf(acc0[0]); q0.y = f2bf(acc0[1]); q0.z = f2bf(acc0[2]); q0.w = f2bf(acc0[3]);
    q1.x = f2bf(acc1[0]); q1.y = f2bf(acc1[1]); q1.z = f2bf(acc1[2]); q1.w = f2bf(acc1[3]);
    *(ushort4*)(dst + ((size_t)(i * CH + lr)) * S_DIM + scol) = q0;
    *(ushort4*)(dst + ((size_t)(i * CH + 16 + lr)) * S_DIM + scol) = q1;
  } else if (b < 1152) {
    // wo2[((ot*32+kk)*64 + lane)*8 + e] = Wo[o = ot*16+(lane&15)]
    //                                       [c*32+d], k' = kk*32+(lane>>4)*8+e
    const int r = b - 1024;  // 0..127
    #pragma unroll
    for (int q = 0; q < 4; q++) {
      const int f = r * 1024 + q * 256 + t;
      const int e = f & 7, l = (f >> 3) & 63, kk = (f >> 9) & 31, ot = f >> 14;
      const int kp = kk * 32 + (l >> 4) * 8 + e;
      const int c = kp & 31, d = kp >> 5;
      const int o = ot * 16 + (l & 15);
      wo2[f] = f2bf(Wo[o * 1024 + c * 32 + d]);
    }
  } else {
    const int i = b - 1152;  // 0..255
    float acc = 0.f;
    #pragma unroll 8
    for (int s = 0; s < S_DIM; s++)
      acc += mask[s * N_DIM + i] * mask[s * N_DIM + t];
    acc = fmaxf(acc, 1.0f);
    rnm[i * N_DIM + t] = 1.0f / acc;
  }
}

// ---------------------------------------------------------------------------
// Kernel B: fused z-GEMM + Wo contraction, 256x256 z-tile = 64 pairs (8i x 8j).
// 1024 threads = 16 waves, 128 KB dynamic LDS, 1 block/CU, grid 32x32 = 1024.
//   stage  : sA/sB 64 KB each (XOR-swizzled 16B granules)
//   GEMM1  : wave grid 4x4, each wave 64x64 of the 256x256 tile, K=128
//   transp : C/D-layout accs -> sZ[pair][k'=d*32+c] (b64 writes, overlays sA+sB)
//   GEMM2  : wave = (o-tile w>>1, pair-half w&1): 2 M-frags x 16 o x K=1024
// ---------------------------------------------------------------------------
__global__ __launch_bounds__(1024, 4) void fused_kernel(
    const unsigned short* __restrict__ a_t, const unsigned short* __restrict__ b_t,
    const unsigned short* __restrict__ wo2, const float* __restrict__ rnm,
    const float* __restrict__ bo, float* __restrict__ out) {
  extern __shared__ __align__(16) unsigned short smem[];
  unsigned short* sA = smem;            // 256 rows x 128 = 64 KB
  unsigned short* sB = smem + 32768;    // 256 rows x 128 = 64 KB
  unsigned short* sZ = smem;            // 64 pairs x 1024 = 128 KB (overlay)

  const int t = threadIdx.x, w = t >> 6, l = t & 63;
  const int lq = l >> 4, lr = l & 15;
  const int bx = blockIdx.x, by = blockIdx.y;

  // Stage: 4096 granules per tile; swizzle g' = g ^ (r&15)
  const unsigned short* srcA = a_t + (size_t)bx * 32768;
  const unsigned short* srcB = b_t + (size_t)by * 32768;
  #pragma unroll
  for (int it = 0; it < 4; it++) {
    const int idx = it * 1024 + t;       // granule 0..4095
    const int r = idx >> 4, g = idx & 15;
    const int dst = r * 128 + ((g ^ (r & 15)) * 8);
    *(bf16x8*)(&sA[dst]) = *(const bf16x8*)(srcA + idx * 8);
    *(bf16x8*)(&sB[dst]) = *(const bf16x8*)(srcB + idx * 8);
  }
  __syncthreads();

  // GEMM1: K = 128 = 4 MFMA k-steps. Wave (wy,wx) owns 64x64.
  const int wy = (w >> 2) * 64, wx = (w & 3) * 64;
  f32x4 acc[4][4];
  #pragma unroll
  for (int a = 0; a < 4; a++)
    #pragma unroll
    for (int c = 0; c < 4; c++) acc[a][c] = (f32x4){0.f, 0.f, 0.f, 0.f};

  #pragma unroll
  for (int ks = 0; ks < 4; ks++) {
    const int g0 = ks * 4 + lq;
    bf16x8 afr[4], bfr[4];
    #pragma unroll
    for (int a = 0; a < 4; a++) {
      const int ra = wy + a * 16 + lr;
      afr[a] = *(const bf16x8*)(&sA[ra * 128 + ((g0 ^ (ra & 15)) * 8)]);
      const int rb = wx + a * 16 + lr;
      bfr[a] = *(const bf16x8*)(&sB[rb * 128 + ((g0 ^ (rb & 15)) * 8)]);
    }
    #pragma unroll
    for (int a = 0; a < 4; a++)
      #pragma unroll
      for (int c = 0; c < 4; c++)
        acc[a][c] = __builtin_amdgcn_mfma_f32_16x16x32_bf16(afr[a], bfr[c], acc[a][c], 0, 0, 0);
  }
  __syncthreads();  // all GEMM1 reads done before sZ overlays sA/sB

  // Transpose: acc (C/D layout) -> sZ[pair][k'=d*32+c], b64 writes.
  // Granule map within a 128-granule pair-row: gp = (g&~7)|((g^(g>>3)^pair)&7)
  #pragma unroll
  for (int a = 0; a < 4; a++) {
    #pragma unroll
    for (int c = 0; c < 4; c++) {
      const int zrb = wy + a * 16 + lq * 4;          // (i_loc,c) base, r = +0..3
      const int zc  = wx + c * 16 + lr;              // (j_loc,d)
      const int pair = (zrb >> 5) * 8 + (zc >> 5);   // 0..63
      const int off = (zc & 31) * 32 + (zrb & 31);   // k' = d*32 + c
      const int g = off >> 3;
      const int gp = (g & ~7) | ((g ^ (g >> 3) ^ pair) & 7);
      ushort4 q;
      q.x = f2bf(acc[a][c][0]); q.y = f2bf(acc[a][c][1]);
      q.z = f2bf(acc[a][c][2]); q.w = f2bf(acc[a][c][3]);
      *(ushort4*)(&sZ[pair * 1024 + gp * 8 + (off & 7)]) = q;
    }
  }
  __syncthreads();

  // GEMM2: wave = (ot = w>>1 -> o-tile of 16, wm2 = w&1 -> 32-pair half).
  // 2 M-frags share each Wo fragment; K = 1024 = 32 MFMA steps.
  const int ot = w >> 1, wm2 = w & 1;
  const int p0 = wm2 * 32 + lr, p1 = p0 + 16;
  const unsigned short* wbase = wo2 + (size_t)ot * 16384 + (size_t)l * 8;
  f32x4 oa[2][2];
  oa[0][0] = oa[0][1] = oa[1][0] = oa[1][1] = (f32x4){0.f, 0.f, 0.f, 0.f};
  #pragma unroll 4
  for (int kk = 0; kk < 32; kk++) {
    const int g = kk * 4 + lq;
    const int gp0 = (g & ~7) | ((g ^ (g >> 3) ^ p0) & 7);
    const int gp1 = (g & ~7) | ((g ^ (g >> 3) ^ p1) & 7);
    const bf16x8 wf = *(const bf16x8*)(wbase + kk * 512);
    const bf16x8 z0 = *(const bf16x8*)(&sZ[p0 * 1024 + gp0 * 8]);
    const bf16x8 z1 = *(const bf16x8*)(&sZ[p1 * 1024 + gp1 * 8]);
    oa[0][kk & 1] = __builtin_amdgcn_mfma_f32_16x16x32_bf16(z0, wf, oa[0][kk & 1], 0, 0, 0);
    oa[1][kk & 1] = __builtin_amdgcn_mfma_f32_16x16x32_bf16(z1, wf, oa[1][kk & 1], 0, 0, 0);
  }

  // Epilogue: D row = pair-in-frag (lq*4+r), col = o (lr)
  const int o = ot * 16 + lr;
  const float bov = bo[o];
  #pragma unroll
  for (int f = 0; f < 2; f++) {
    #pragma unroll
    for (int r = 0; r < 4; r++) {
      const int pair = wm2 * 32 + f * 16 + lq * 4 + r;
      const int ii = bx * 8 + (pair >> 3);
      const int jj = by * 8 + (pair & 7);
      const float sc = rnm[ii * N_DIM + jj];
      out[((size_t)(ii * N_DIM + jj)) * COUT + o] =
          (oa[f][0][r] + oa[f][1][r]) * sc + bov;
    }
  }
}

// ---------------------------------------------------------------------------
extern "C" void kernel_launch(void* const* d_in, const int* in_sizes, int n_in,
                              void* d_out, int out_size, void* d_ws, size_t ws_size,
                              hipStream_t stream) {
  const float* m     = (const float*)d_in[0];
  const float* mask  = (const float*)d_in[1];
  const float* gamma = (const float*)d_in[2];
  const float* beta  = (const float*)d_in[3];
  const float* Wa    = (const float*)d_in[4];
  const float* Wb    = (const float*)d_in[5];
  const float* Wo    = (const float*)d_in[6];
  const float* bo    = (const float*)d_in[7];
  float* out = (float*)d_out;

  char* ws = (char*)d_ws;
  float*          rnm = (float*)(ws);                     // 256 KB
  unsigned short* wo2 = (unsigned short*)(ws + 262144);   // 256 KB
  unsigned short* a_t = (unsigned short*)(ws + 524288);   //   2 MB
  unsigned short* b_t = (unsigned short*)(ws + 2621440);  //   2 MB

  // Raise dynamic-LDS cap (idempotent; host-side, not a stream op)
  hipFuncSetAttribute((const void*)fused_kernel,
                      hipFuncAttributeMaxDynamicSharedMemorySize, 131072);

  lnp_prep_kernel<<<1408, 256, 0, stream>>>(m, mask, gamma, beta, Wa, Wb, Wo,
                                            rnm, wo2, a_t, b_t);
  fused_kernel<<<dim3(32, 32), 1024, 131072, stream>>>(a_t, b_t, wo2, rnm, bo, out);
}